// Round 1
// baseline (2278.353 us; speedup 1.0000x reference)
//
#include <hip/hip_runtime.h>
#include <cstdint>

// ---------------- fast device math (raw v_exp_f32 / v_rcp_f32) ----------------
__device__ __forceinline__ float fexp2(float x) { return __builtin_amdgcn_exp2f(x); }
__device__ __forceinline__ float frcp(float x)  { return __builtin_amdgcn_rcpf(x); }

__device__ __forceinline__ float fast_tanh(float x) {
    x = fminf(15.0f, fmaxf(-15.0f, x));
    float E = fexp2(x * 2.8853900817779268f);   // exp(2x) = 2^(2x*log2e)
    float d = E + 1.0f;
    float r = frcp(d);
    r = r * (2.0f - d * r);                      // Newton -> ~fp32 precise
    return (E - 1.0f) * r;
}

// ---------------- tiled fp32 GEMM: C[M][N] = act(A[M][K] @ W[K][N] + bias) ----
// BM=64 BN=64 BK=16, 256 threads, 4x4 micro-tile per thread.
#define BM 64
#define BN 64
#define BK 16

template<bool TANH>
__global__ __launch_bounds__(256) void gemm_bias(
    const float* __restrict__ A, const float* __restrict__ W,
    const float* __restrict__ bias, float* __restrict__ C,
    int M, int N, int K)
{
    __shared__ float As[BK][BM + 4];   // stride 68: 16B-aligned quads, low bank conflict
    __shared__ float Bs[BK][BN + 4];

    const int tid = threadIdx.x;
    const int tx = tid & 15;          // n-quad
    const int ty = tid >> 4;          // m-quad
    const int m0 = blockIdx.y * BM;
    const int n0 = blockIdx.x * BN;

    float acc[4][4] = {};

    for (int k0 = 0; k0 < K; k0 += BK) {
        // stage A tile (transposed into LDS: As[k][m])
        #pragma unroll
        for (int ld = 0; ld < 4; ++ld) {
            int e  = tid + ld * 256;        // 0..1023
            int kk = e & 15, mm = e >> 4;
            int kg = k0 + kk;
            As[kk][mm] = (kg < K) ? A[(size_t)(m0 + mm) * K + kg] : 0.0f;
        }
        // stage B tile (Bs[k][n])
        #pragma unroll
        for (int ld = 0; ld < 4; ++ld) {
            int e  = tid + ld * 256;
            int nn = e & 63, kk = e >> 6;
            int kg = k0 + kk, ng = n0 + nn;
            Bs[kk][nn] = (kg < K && ng < N) ? W[(size_t)kg * N + ng] : 0.0f;
        }
        __syncthreads();

        #pragma unroll
        for (int kk = 0; kk < BK; ++kk) {
            float4 a  = *(const float4*)&As[kk][ty * 4];
            float4 bq = *(const float4*)&Bs[kk][tx * 4];
            float av[4] = {a.x, a.y, a.z, a.w};
            float bv[4] = {bq.x, bq.y, bq.z, bq.w};
            #pragma unroll
            for (int i2 = 0; i2 < 4; ++i2)
                #pragma unroll
                for (int j2 = 0; j2 < 4; ++j2)
                    acc[i2][j2] += av[i2] * bv[j2];
        }
        __syncthreads();
    }

    const int cbase = n0 + tx * 4;
    if (cbase >= N) return;

    float bb[4];
    if (cbase + 3 < N) {
        float4 b4 = *(const float4*)&bias[cbase];
        bb[0] = b4.x; bb[1] = b4.y; bb[2] = b4.z; bb[3] = b4.w;
    } else {
        #pragma unroll
        for (int e = 0; e < 4; ++e) bb[e] = (cbase + e < N) ? bias[cbase + e] : 0.0f;
    }

    #pragma unroll
    for (int i2 = 0; i2 < 4; ++i2) {
        int row = m0 + ty * 4 + i2;          // M is a multiple of 64 here
        float o[4];
        #pragma unroll
        for (int j2 = 0; j2 < 4; ++j2) {
            float v = acc[i2][j2] + bb[j2];
            o[j2] = TANH ? fast_tanh(v) : v;
        }
        if (cbase + 3 < N) {
            float4 o4 = {o[0], o[1], o[2], o[3]};
            *(float4*)&C[(size_t)row * N + cbase] = o4;
        } else {
            #pragma unroll
            for (int j2 = 0; j2 < 4; ++j2)
                if (cbase + j2 < N) C[(size_t)row * N + cbase + j2] = o[j2];
        }
    }
}

// ---------------- decoder layer 1 (K=4): O[16384][500] = tanh(Mo[16384][4]@Wd[4][500]+b)
__global__ __launch_bounds__(256) void dec_l1(
    const float* __restrict__ Mo, const float* __restrict__ Wd,
    const float* __restrict__ bd, float* __restrict__ O)
{
    int idx = blockIdx.x * 256 + threadIdx.x;      // one thread per 4 outputs
    int r  = idx / 125;
    int c4 = (idx % 125) * 4;
    float4 m = *(const float4*)&Mo[(size_t)r * 4];
    float4 w0 = *(const float4*)&Wd[0 * 500 + c4];
    float4 w1 = *(const float4*)&Wd[1 * 500 + c4];
    float4 w2 = *(const float4*)&Wd[2 * 500 + c4];
    float4 w3 = *(const float4*)&Wd[3 * 500 + c4];
    float4 b  = *(const float4*)&bd[c4];
    float o0 = b.x + m.x * w0.x + m.y * w1.x + m.z * w2.x + m.w * w3.x;
    float o1 = b.y + m.x * w0.y + m.y * w1.y + m.z * w2.y + m.w * w3.y;
    float o2 = b.z + m.x * w0.z + m.y * w1.z + m.z * w2.z + m.w * w3.z;
    float o3 = b.w + m.x * w0.w + m.y * w1.w + m.z * w2.w + m.w * w3.w;
    float4 o = {fast_tanh(o0), fast_tanh(o1), fast_tanh(o2), fast_tanh(o3)};
    *(float4*)&O[(size_t)r * 500 + c4] = o;
}

// ---------------- LTC scan: 1 workgroup per batch, 512 threads (8 waves) ------
// lane -> postsynaptic j = 8*wave + (l&7); i-group g = l>>3 owns i in [8g,8g+8)
#define SEQ_T 512

__global__ __launch_bounds__(512) void ltc_scan(
    const float* __restrict__ h,       // [32][512][20]
    const float* __restrict__ gleak, const float* __restrict__ vleak,
    const float* __restrict__ cm,
    const float* __restrict__ w,  const float* __restrict__ mu,
    const float* __restrict__ sg, const float* __restrict__ erev,
    const float* __restrict__ sw,  const float* __restrict__ smu,
    const float* __restrict__ ssg, const float* __restrict__ serev,
    const float* __restrict__ in_w, const float* __restrict__ in_b,
    const float* __restrict__ out_w, const float* __restrict__ out_b,
    float* __restrict__ motor)         // [32][512][4]
{
    const int b   = blockIdx.x;
    const int tid = threadIdx.x;
    const int wv  = tid >> 6;
    const int l   = tid & 63;
    const int j   = (wv << 3) | (l & 7);   // 0..63
    const int g   = l >> 3;                // 0..7

    const float LOG2E = 1.4426950408889634f;

    // per-lane unfold params for (i = 8g+r, j)
    float A1[8], B1[8], Wp[8], WE[8];
    #pragma unroll
    for (int r = 0; r < 8; ++r) {
        int i = 8 * g + r;
        float s  = sg[i * 64 + j];
        float m  = mu[i * 64 + j];
        float ww = w [i * 64 + j];
        A1[r] = s * LOG2E;
        B1[r] = m * s * LOG2E;
        Wp[r] = ww;
        WE[r] = ww * erev[i * 64 + j];
    }
    // sensory params: i in {g, g+8, g+16(<20)}
    float sA[3], sB[3], sWp[3], sWE[3], uw[3], ub[3];
    int   sI[3];
    #pragma unroll
    for (int r = 0; r < 3; ++r) {
        int i = g + 8 * r;
        if (i < 20) {
            float s  = ssg[i * 64 + j];
            float m  = smu[i * 64 + j];
            float ww = sw [i * 64 + j];
            sA[r] = s * LOG2E; sB[r] = m * s * LOG2E;
            sWp[r] = ww; sWE[r] = ww * serev[i * 64 + j];
            sI[r] = i;
        } else { sA[r] = 0; sB[r] = 0; sWp[r] = 0; sWE[r] = 0; sI[r] = 0; }
        uw[r] = in_w[sI[r]]; ub[r] = in_b[sI[r]];
    }

    const float cmt  = cm[j] * 6.0f;                 // cm / (1.0/6)
    const float gl   = gleak[j];
    const float glvl = gl * vleak[j];
    const float ow   = out_w[j & 3], ob = out_b[j & 3];

    __shared__ float vbuf[2][64];
    float vj = 0.0f;
    if (tid < 64) { vbuf[0][tid] = 0.0f; vbuf[1][tid] = 0.0f; }
    __syncthreads();

    const float* hb = h + (size_t)b * SEQ_T * 20;
    float* mb = motor + (size_t)b * SEQ_T * 4;

    // prefetch u for t=0
    float u_cur[3];
    #pragma unroll
    for (int r = 0; r < 3; ++r) u_cur[r] = hb[sI[r]];

    int cur = 0;
    for (int t = 0; t < SEQ_T; ++t) {
        // issue next step's u loads early (latency hides under the 6 unfolds)
        float u_nxt[3];
        int tn = (t + 1 < SEQ_T) ? (t + 1) : t;
        #pragma unroll
        for (int r = 0; r < 3; ++r) u_nxt[r] = hb[tn * 20 + sI[r]];

        // sensory synapses (no LDS, butterfly reduce over g)
        float ns = 0.0f, ds = 0.0f;
        #pragma unroll
        for (int r = 0; r < 3; ++r) {
            float ui = u_cur[r] * uw[r] + ub[r];
            float x  = sB[r] - ui * sA[r];
            float E  = fexp2(x);
            float s  = frcp(1.0f + E);
            ns += sWE[r] * s;
            ds += sWp[r] * s;
        }
        #pragma unroll
        for (int msk = 8; msk <= 32; msk <<= 1) {
            ns += __shfl_xor(ns, msk, 64);
            ds += __shfl_xor(ds, msk, 64);
        }

        // 6 semi-implicit ODE unfolds
        #pragma unroll 1
        for (int uf = 0; uf < 6; ++uf) {
            float4 va = *(const float4*)&vbuf[cur][8 * g];
            float4 vc = *(const float4*)&vbuf[cur][8 * g + 4];
            float vv[8] = {va.x, va.y, va.z, va.w, vc.x, vc.y, vc.z, vc.w};
            float an = 0.0f, ad = 0.0f;
            #pragma unroll
            for (int r = 0; r < 8; ++r) {
                float x = B1[r] - vv[r] * A1[r];
                float E = fexp2(x);
                float s = frcp(1.0f + E);
                an += WE[r] * s;
                ad += Wp[r] * s;
            }
            #pragma unroll
            for (int msk = 8; msk <= 32; msk <<= 1) {
                an += __shfl_xor(an, msk, 64);
                ad += __shfl_xor(ad, msk, 64);
            }
            float num = cmt * vj + glvl + an + ns;
            float den = cmt + gl + ad + ds + 1e-8f;
            float r0  = frcp(den);
            r0 = r0 * (2.0f - den * r0);          // Newton -> fp32-accurate divide
            vj = num * r0;
            if (g == 0) vbuf[cur ^ 1][j] = vj;
            __syncthreads();
            cur ^= 1;
        }

        if (g == 0 && j < 4) mb[t * 4 + j] = vj * ow + ob;

        #pragma unroll
        for (int r = 0; r < 3; ++r) u_cur[r] = u_nxt[r];
    }
}

// ---------------- launch --------------------------------------------------
extern "C" void kernel_launch(void* const* d_in, const int* in_sizes, int n_in,
                              void* d_out, int out_size, void* d_ws, size_t ws_size,
                              hipStream_t stream) {
    const float* x      = (const float*)d_in[0];
    const float* enc_w0 = (const float*)d_in[1];
    const float* enc_b0 = (const float*)d_in[2];
    const float* enc_w1 = (const float*)d_in[3];
    const float* enc_b1 = (const float*)d_in[4];
    const float* enc_w2 = (const float*)d_in[5];
    const float* enc_b2 = (const float*)d_in[6];
    const float* dec_w0 = (const float*)d_in[7];
    const float* dec_b0 = (const float*)d_in[8];
    const float* dec_w1 = (const float*)d_in[9];
    const float* dec_b1 = (const float*)d_in[10];
    const float* dec_w2 = (const float*)d_in[11];
    const float* dec_b2 = (const float*)d_in[12];
    const float* gleak  = (const float*)d_in[13];
    const float* vleak  = (const float*)d_in[14];
    const float* cm     = (const float*)d_in[15];
    const float* w      = (const float*)d_in[16];
    const float* mu     = (const float*)d_in[17];
    const float* sigma  = (const float*)d_in[18];
    const float* erev   = (const float*)d_in[19];
    const float* sw     = (const float*)d_in[20];
    const float* smu    = (const float*)d_in[21];
    const float* ssigma = (const float*)d_in[22];
    const float* serev  = (const float*)d_in[23];
    const float* in_w   = (const float*)d_in[24];
    const float* in_b   = (const float*)d_in[25];
    const float* out_w  = (const float*)d_in[26];
    const float* out_b  = (const float*)d_in[27];

    float* ws   = (float*)d_ws;
    float* buf1 = ws;                       // 16384*500
    float* buf2 = ws + 8192000;             // 16384*500
    float* hbuf = ws + 16384000;            // 16384*20
    float* mbuf = ws + 16384000 + 327680;   // 16384*4  (total 64 MB)

    dim3 blk(256);
    // encoder
    gemm_bias<true ><<<dim3(8, 256), blk, 0, stream>>>(x,    enc_w0, enc_b0, buf1, 16384, 500, 39);
    gemm_bias<true ><<<dim3(8, 256), blk, 0, stream>>>(buf1, enc_w1, enc_b1, buf2, 16384, 500, 500);
    gemm_bias<false><<<dim3(1, 256), blk, 0, stream>>>(buf2, enc_w2, enc_b2, hbuf, 16384, 20, 500);
    // LTC scan
    ltc_scan<<<dim3(32), dim3(512), 0, stream>>>(hbuf, gleak, vleak, cm, w, mu, sigma, erev,
                                                 sw, smu, ssigma, serev, in_w, in_b, out_w, out_b, mbuf);
    // decoder
    dec_l1<<<dim3(8000), blk, 0, stream>>>(mbuf, dec_w0, dec_b0, buf1);
    gemm_bias<true ><<<dim3(8, 256), blk, 0, stream>>>(buf1, dec_w1, dec_b1, buf2, 16384, 500, 500);
    gemm_bias<false><<<dim3(1, 256), blk, 0, stream>>>(buf2, dec_w2, dec_b2, (float*)d_out, 16384, 30, 500);
}